// Round 1
// baseline (10374.561 us; speedup 1.0000x reference)
//
#include <hip/hip_runtime.h>
#include <hip/hip_fp16.h>

#define B_ 64
#define T_ 512
#define EMB_ 128
#define HID_ 256
#define MEL_ 80
#define KT_W 12   // k-tiles of 32 over K=384

typedef __attribute__((ext_vector_type(8))) _Float16 half8;
typedef __attribute__((ext_vector_type(4))) float f32x4;

__device__ __forceinline__ float sigf(float x) {
  x = fminf(fmaxf(x, -30.f), 30.f);
  return 1.f / (1.f + __expf(-x));
}
__device__ __forceinline__ float tanhf_(float x) {
  x = fminf(fmaxf(x, -15.f), 15.f);
  float e = __expf(2.f * x);
  return (e - 1.f) / (e + 1.f);
}

// Pack W = [wih | whh] (per dir, 1024x384 fp32) into MFMA B-fragment order:
// Wp[((dir*64+g16)*12+kt)*512 + lane*8 + j] = W[g16*16+(lane&15)][kt*32+(lane>>4)*8+j]
__global__ void k_pack_w(const float* __restrict__ wih_f, const float* __restrict__ whh_f,
                         const float* __restrict__ wih_b, const float* __restrict__ whh_b,
                         _Float16* __restrict__ Wp) {
  int tid = blockIdx.x * 256 + threadIdx.x;  // 98304 total
  int lane = tid & 63;
  int r = tid >> 6;
  int kt = r % 12; r /= 12;
  int g16 = r % 64;
  int dir = r / 64;
  if (dir >= 2) return;
  const float* wih = dir ? wih_b : wih_f;
  const float* whh = dir ? whh_b : whh_f;
  int n = g16 * 16 + (lane & 15);
  int kbase = kt * 32 + (lane >> 4) * 8;
  _Float16* dst = Wp + (size_t)tid * 8;
#pragma unroll
  for (int j = 0; j < 8; ++j) {
    int k = kbase + j;
    float v = (k < EMB_) ? wih[n * EMB_ + k] : whh[n * HID_ + (k - EMB_)];
    dst[j] = (_Float16)v;
  }
}

// bsum[dir*1024+g] = bih+bhh ; linWp packed B-fragments of lin_w (80x512)
__global__ void k_pack_misc(const float* __restrict__ bih_f, const float* __restrict__ bhh_f,
                            const float* __restrict__ bih_b, const float* __restrict__ bhh_b,
                            const float* __restrict__ lin_w, float* __restrict__ bsum,
                            _Float16* __restrict__ linWp) {
  int t = blockIdx.x * 256 + threadIdx.x;
  if (t < 2048) {
    int dir = t >> 10, g = t & 1023;
    bsum[t] = dir ? (bih_b[g] + bhh_b[g]) : (bih_f[g] + bhh_f[g]);
  } else if (t < 2048 + 5120) {
    int u = t - 2048;
    int lane = u & 63;
    int r = u >> 6;
    int kt = r % 16, nt = r / 16;  // nt<5, kt<16 over K=512
    int n = nt * 16 + (lane & 15);
    int kbase = kt * 32 + (lane >> 4) * 8;
    _Float16* dst = linWp + (size_t)u * 8;
#pragma unroll
    for (int j = 0; j < 8; ++j) dst[j] = (_Float16)lin_w[n * 512 + kbase + j];
  }
}

__global__ void k_dur(const int* __restrict__ x, const float* __restrict__ embed,
                      const float* __restrict__ dp_w, const float* __restrict__ dp_b,
                      int* __restrict__ dur) {
  int gid = blockIdx.x * 256 + threadIdx.x;
  if (gid >= B_ * T_) return;
  const float* er = embed + (size_t)x[gid] * EMB_;
  float d = 0.f;
  for (int e = 0; e < EMB_; ++e) d += er[e] * dp_w[e];
  d += dp_b[0];
  d = fmaxf(d, 0.f);
  dur[gid] = (int)floorf(d) + 1;
}

__global__ void k_scan(const int* __restrict__ dur, int* __restrict__ cum) {
  __shared__ int s[512];
  int b = blockIdx.x, t = threadIdx.x;
  s[t] = dur[b * 512 + t];
  __syncthreads();
  for (int off = 1; off < 512; off <<= 1) {
    int v = (t >= off) ? s[t - off] : 0;
    __syncthreads();
    s[t] += v;
    __syncthreads();
  }
  cum[b * 512 + t] = s[t];
}

__global__ void k_fill(int* __restrict__ idx, int n) {
  int gid = blockIdx.x * 256 + threadIdx.x;
  if (gid < n) idx[gid] = -1;
}

__global__ void k_scatter(const int* __restrict__ cum, int* __restrict__ idx, int L) {
  int b = blockIdx.x, t = threadIdx.x;
  int c1 = cum[b * 512 + t];
  int c0 = t ? cum[b * 512 + t - 1] : 0;
  for (int p = c0; p < c1; ++p)
    if (p < L) idx[(size_t)b * L + p] = t;
}

__global__ void k_expand(const int* __restrict__ x, const float* __restrict__ embed,
                         const int* __restrict__ idx, _Float16* __restrict__ expb, int L) {
  int gid = blockIdx.x * 256 + threadIdx.x;
  if (gid >= B_ * L * 16) return;
  int ch = gid & 15;
  int rem = gid >> 4;
  int l = rem % L;
  int b = rem / L;
  int ix = idx[(size_t)b * L + l];
  half8 v;
  if (ix < 0) {
#pragma unroll
    for (int j = 0; j < 8; ++j) v[j] = (_Float16)0.f;
  } else {
    const float* er = embed + (size_t)x[b * 512 + ix] * EMB_ + ch * 8;
#pragma unroll
    for (int j = 0; j < 8; ++j) v[j] = (_Float16)er[j];
  }
  *(half8*)(expb + ((size_t)b * L + l) * EMB_ + ch * 8) = v;
}

// 8 blocks = 2 dirs x 4 batch-groups (16 batches each). 512 threads = 8 waves.
// Per step: A=[x_t | h] (16x384 f16 in LDS), W streamed from L2 in packed frag
// order, gates -> LDS (f16), cell update in fp32 regs (c resident), h -> LDS+global.
__global__ __launch_bounds__(512) void k_recurrent(
    const _Float16* __restrict__ expb, const _Float16* __restrict__ Wp,
    const float* __restrict__ bsum, _Float16* __restrict__ hcat, int L) {
  __shared__ _Float16 Ash[16][392];   // 16 rows x (384+8 pad)
  __shared__ _Float16 gsh[16][1040];  // gate pre-acts (1024 + pad)
  int tid = threadIdx.x;
  int dir = blockIdx.x >> 2, bg = blockIdx.x & 3;
  int wv = tid >> 6, lane = tid & 63;
  int arow = lane & 15, kgrp = lane >> 4;
  for (int i = tid; i < 16 * 392; i += 512) (&Ash[0][0])[i] = (_Float16)0.f;
  // cell-phase mapping: thread owns (batch cm, hidden units jb*8..jb*8+7)
  int cm = tid & 15, jb = tid >> 4;  // jb in 0..31
  float bi[4][8], creg[8];
#pragma unroll
  for (int g = 0; g < 4; ++g)
#pragma unroll
    for (int u = 0; u < 8; ++u) bi[g][u] = bsum[dir * 1024 + g * 256 + jb * 8 + u];
#pragma unroll
  for (int u = 0; u < 8; ++u) creg[u] = 0.f;
  const _Float16* Wd = Wp + (size_t)dir * 64 * KT_W * 512;
  __syncthreads();
  for (int s = 0; s < L; ++s) {
    int l_io = dir ? (L - 1 - s) : s;
    if (tid < 256) {  // load x_t into A[:, 0:128]
      int m = tid >> 4, ch = tid & 15;
      half8 v = *(const half8*)(expb + ((size_t)(bg * 16 + m) * L + l_io) * EMB_ + ch * 8);
      *(half8*)&Ash[m][ch * 8] = v;
    }
    __syncthreads();
    // GEMM: wave wv owns gate tiles wv*8 .. wv*8+7 (16 gates each), processed in pairs
#pragma unroll
    for (int pr = 0; pr < 4; ++pr) {
      int t0 = wv * 8 + pr * 2;
      f32x4 acc0 = {0.f, 0.f, 0.f, 0.f}, acc1 = {0.f, 0.f, 0.f, 0.f};
      const half8* B0 = (const half8*)(Wd + (size_t)t0 * KT_W * 512) + lane;
      const half8* B1 = B0 + KT_W * 64;
#pragma unroll
      for (int kt = 0; kt < KT_W; ++kt) {
        half8 a = *(const half8*)&Ash[arow][kt * 32 + kgrp * 8];
        half8 b0 = B0[kt * 64];
        half8 b1 = B1[kt * 64];
        acc0 = __builtin_amdgcn_mfma_f32_16x16x32_f16(a, b0, acc0, 0, 0, 0);
        acc1 = __builtin_amdgcn_mfma_f32_16x16x32_f16(a, b1, acc1, 0, 0, 0);
      }
      int n0 = t0 * 16 + arow;
#pragma unroll
      for (int i = 0; i < 4; ++i) {
        gsh[kgrp * 4 + i][n0] = (_Float16)acc0[i];
        gsh[kgrp * 4 + i][n0 + 16] = (_Float16)acc1[i];
      }
    }
    __syncthreads();
    // cell update (all 512 threads: 16 batches x 32 j-blocks)
    {
      half8 gi = *(const half8*)&gsh[cm][jb * 8];
      half8 gf = *(const half8*)&gsh[cm][256 + jb * 8];
      half8 gg = *(const half8*)&gsh[cm][512 + jb * 8];
      half8 go = *(const half8*)&gsh[cm][768 + jb * 8];
      half8 hv;
#pragma unroll
      for (int u = 0; u < 8; ++u) {
        float iv = (float)gi[u] + bi[0][u];
        float fv = (float)gf[u] + bi[1][u];
        float gv = (float)gg[u] + bi[2][u];
        float ov = (float)go[u] + bi[3][u];
        float c = sigf(fv) * creg[u] + sigf(iv) * tanhf_(gv);
        float h = sigf(ov) * tanhf_(c);
        creg[u] = c;
        hv[u] = (_Float16)h;
      }
      *(half8*)&Ash[cm][EMB_ + jb * 8] = hv;
      *(half8*)(hcat + ((size_t)(bg * 16 + cm) * L + l_io) * 512 + dir * 256 + jb * 8) = hv;
    }
    __syncthreads();
  }
}

// out[r,:80] = hcat[r,:512] @ lin_w.T + lin_b ; one wave per 16-row M-tile
__global__ __launch_bounds__(256) void k_linear(
    const _Float16* __restrict__ hcat, const _Float16* __restrict__ linWp,
    const float* __restrict__ lin_b, float* __restrict__ out, int L) {
  int tid = threadIdx.x;
  int wv = tid >> 6, lane = tid & 63;
  int arow = lane & 15, kgrp = lane >> 4;
  int mt = blockIdx.x * 4 + wv;  // < 4L
  half8 a[16];
  const _Float16* abase = hcat + (size_t)(mt * 16 + arow) * 512 + kgrp * 8;
#pragma unroll
  for (int kt = 0; kt < 16; ++kt) a[kt] = *(const half8*)(abase + kt * 32);
#pragma unroll
  for (int nt = 0; nt < 5; ++nt) {
    f32x4 acc = {0.f, 0.f, 0.f, 0.f};
    const half8* Bp = (const half8*)(linWp + (size_t)nt * 16 * 512) + lane;
#pragma unroll
    for (int kt = 0; kt < 16; ++kt)
      acc = __builtin_amdgcn_mfma_f32_16x16x32_f16(a[kt], Bp[kt * 64], acc, 0, 0, 0);
    int col = nt * 16 + arow;
    float bb = lin_b[col];
#pragma unroll
    for (int i = 0; i < 4; ++i)
      out[(size_t)(mt * 16 + kgrp * 4 + i) * MEL_ + col] = acc[i] + bb;
  }
}

extern "C" void kernel_launch(void* const* d_in, const int* in_sizes, int n_in,
                              void* d_out, int out_size, void* d_ws, size_t ws_size,
                              hipStream_t stream) {
  const int* x = (const int*)d_in[0];
  const float* embed = (const float*)d_in[1];
  const float* dp_w = (const float*)d_in[2];
  const float* dp_b = (const float*)d_in[3];
  const float* wih_f = (const float*)d_in[4];
  const float* whh_f = (const float*)d_in[5];
  const float* bih_f = (const float*)d_in[6];
  const float* bhh_f = (const float*)d_in[7];
  const float* wih_b = (const float*)d_in[8];
  const float* whh_b = (const float*)d_in[9];
  const float* bih_b = (const float*)d_in[10];
  const float* bhh_b = (const float*)d_in[11];
  const float* lin_w = (const float*)d_in[12];
  const float* lin_b = (const float*)d_in[13];
  float* out = (float*)d_out;
  (void)in_sizes; (void)n_in; (void)ws_size;

  int L = out_size / (B_ * MEL_);
  char* base = (char*)d_ws;
  size_t o = 0;
  auto take = [&](size_t bytes) {
    void* p = base + o;
    o = (o + bytes + 255) & ~(size_t)255;
    return p;
  };
  int* dur = (int*)take((size_t)B_ * T_ * 4);
  int* cum = (int*)take((size_t)B_ * T_ * 4);
  int* idx = (int*)take((size_t)B_ * L * 4);
  _Float16* Wp = (_Float16*)take((size_t)2 * 64 * KT_W * 512 * 2);
  float* bsum = (float*)take(2048 * 4);
  _Float16* linWp = (_Float16*)take((size_t)5 * 16 * 512 * 2);
  _Float16* expb = (_Float16*)take((size_t)B_ * L * EMB_ * 2);
  _Float16* hcat = (_Float16*)take((size_t)B_ * L * 512 * 2);

  hipLaunchKernelGGL(k_pack_w, dim3(384), dim3(256), 0, stream, wih_f, whh_f, wih_b, whh_b, Wp);
  hipLaunchKernelGGL(k_pack_misc, dim3(28), dim3(256), 0, stream, bih_f, bhh_f, bih_b, bhh_b,
                     lin_w, bsum, linWp);
  hipLaunchKernelGGL(k_dur, dim3(128), dim3(256), 0, stream, x, embed, dp_w, dp_b, dur);
  hipLaunchKernelGGL(k_scan, dim3(64), dim3(512), 0, stream, dur, cum);
  hipLaunchKernelGGL(k_fill, dim3((B_ * L + 255) / 256), dim3(256), 0, stream, idx, B_ * L);
  hipLaunchKernelGGL(k_scatter, dim3(64), dim3(512), 0, stream, cum, idx, L);
  hipLaunchKernelGGL(k_expand, dim3((B_ * L * 16 + 255) / 256), dim3(256), 0, stream,
                     x, embed, idx, expb, L);
  hipLaunchKernelGGL(k_recurrent, dim3(8), dim3(512), 0, stream, expb, Wp, bsum, hcat, L);
  hipLaunchKernelGGL(k_linear, dim3(L), dim3(256), 0, stream, hcat, linWp, lin_b, out, L);
}

// Round 2
// 6265.253 us; speedup vs baseline: 1.6559x; 1.6559x over previous
//
#include <hip/hip_runtime.h>
#include <hip/hip_fp16.h>

#define B_ 64
#define T_ 512
#define EMB_ 128
#define HID_ 256
#define MEL_ 80

typedef __attribute__((ext_vector_type(8))) _Float16 half8;
typedef __attribute__((ext_vector_type(4))) float f32x4;

__device__ __forceinline__ float sigf(float x) {
  x = fminf(fmaxf(x, -30.f), 30.f);
  return 1.f / (1.f + __expf(-x));
}
__device__ __forceinline__ float tanhf_(float x) {
  x = fminf(fmaxf(x, -15.f), 15.f);
  float e = __expf(2.f * x);
  return (e - 1.f) / (e + 1.f);
}

// Pack W = [wih | whh] (per dir, 1024x384) into MFMA B-frags, rows permuted to
// gu-order: for (dir,slice), gu = nt*16+c maps to row g*256+slice*64+u where
// g=gu>>6, u=gu&63. Layout: Wall[((ds*16+nt)*12+kt)*64 + lane][8]
__global__ void k_pack_wall(const float* __restrict__ wih_f, const float* __restrict__ whh_f,
                            const float* __restrict__ wih_b, const float* __restrict__ whh_b,
                            _Float16* __restrict__ Wall) {
  int tid = blockIdx.x * 256 + threadIdx.x;  // 98304 total
  int lane = tid & 63;
  int r = tid >> 6;
  int kt = r % 12; r /= 12;
  int nt = r % 16; r /= 16;
  int ds = r;  // 0..7
  if (ds >= 8) return;
  int dir = ds >> 2, slice = ds & 3;
  const float* wih = dir ? wih_b : wih_f;
  const float* whh = dir ? whh_b : whh_f;
  int gu = nt * 16 + (lane & 15);
  int g = gu >> 6, u = gu & 63;
  int row = g * 256 + slice * 64 + u;
  int kbase = kt * 32 + (lane >> 4) * 8;
  _Float16* dst = Wall + (size_t)tid * 8;
#pragma unroll
  for (int j = 0; j < 8; ++j) {
    int k = kbase + j;
    float v = (k < EMB_) ? wih[row * EMB_ + k] : whh[row * HID_ + (k - EMB_)];
    dst[j] = (_Float16)v;
  }
}

__global__ void k_pack_misc(const float* __restrict__ bih_f, const float* __restrict__ bhh_f,
                            const float* __restrict__ bih_b, const float* __restrict__ bhh_b,
                            const float* __restrict__ lin_w, float* __restrict__ bsum,
                            _Float16* __restrict__ linWp) {
  int t = blockIdx.x * 256 + threadIdx.x;
  if (t < 2048) {
    int dir = t >> 10, g = t & 1023;
    bsum[t] = dir ? (bih_b[g] + bhh_b[g]) : (bih_f[g] + bhh_f[g]);
  } else if (t < 2048 + 5120) {
    int u = t - 2048;
    int lane = u & 63;
    int r = u >> 6;
    int kt = r % 16, nt = r / 16;
    int n = nt * 16 + (lane & 15);
    int kbase = kt * 32 + (lane >> 4) * 8;
    _Float16* dst = linWp + (size_t)u * 8;
#pragma unroll
    for (int j = 0; j < 8; ++j) dst[j] = (_Float16)lin_w[n * 512 + kbase + j];
  }
}

__global__ void k_dur(const int* __restrict__ x, const float* __restrict__ embed,
                      const float* __restrict__ dp_w, const float* __restrict__ dp_b,
                      int* __restrict__ dur) {
  int gid = blockIdx.x * 256 + threadIdx.x;
  if (gid >= B_ * T_) return;
  const float* er = embed + (size_t)x[gid] * EMB_;
  float d = 0.f;
  for (int e = 0; e < EMB_; ++e) d += er[e] * dp_w[e];
  d += dp_b[0];
  d = fmaxf(d, 0.f);
  dur[gid] = (int)floorf(d) + 1;
}

__global__ void k_scan(const int* __restrict__ dur, int* __restrict__ cum) {
  __shared__ int s[512];
  int b = blockIdx.x, t = threadIdx.x;
  s[t] = dur[b * 512 + t];
  __syncthreads();
  for (int off = 1; off < 512; off <<= 1) {
    int v = (t >= off) ? s[t - off] : 0;
    __syncthreads();
    s[t] += v;
    __syncthreads();
  }
  cum[b * 512 + t] = s[t];
}

__global__ void k_fill(int* __restrict__ p, int n, int v) {
  int gid = blockIdx.x * 256 + threadIdx.x;
  if (gid < n) p[gid] = v;
}

__global__ void k_scatter(const int* __restrict__ cum, int* __restrict__ idx, int L) {
  int b = blockIdx.x, t = threadIdx.x;
  int c1 = cum[b * 512 + t];
  int c0 = t ? cum[b * 512 + t - 1] : 0;
  for (int p = c0; p < c1; ++p)
    if (p < L) idx[(size_t)b * L + p] = t;
}

__global__ void k_expand(const int* __restrict__ x, const float* __restrict__ embed,
                         const int* __restrict__ idx, _Float16* __restrict__ expb, int L) {
  int gid = blockIdx.x * 256 + threadIdx.x;
  if (gid >= B_ * L * 16) return;
  int ch = gid & 15;
  int rem = gid >> 4;
  int l = rem % L;
  int b = rem / L;
  int ix = idx[(size_t)b * L + l];
  half8 v;
  if (ix < 0) {
#pragma unroll
    for (int j = 0; j < 8; ++j) v[j] = (_Float16)0.f;
  } else {
    const float* er = embed + (size_t)x[b * 512 + ix] * EMB_ + ch * 8;
#pragma unroll
    for (int j = 0; j < 8; ++j) v[j] = (_Float16)er[j];
  }
  *(half8*)(expb + ((size_t)b * L + l) * EMB_ + ch * 8) = v;
}

// 8 blocks = 2 dirs x 4 hidden-slices (64 units each). 256 threads = 4 waves,
// 1 wave/SIMD -> up to 512 VGPRs. Weights live in VGPRs for the whole kernel.
// Wave w owns n-tiles {w,w+4,w+8,w+12} = gates i,f,g,o of units [w*16,w*16+16),
// so the cell update happens in the MFMA output registers (no gate LDS).
// h exchanged across slice-blocks via hcat + release/acquire flags.
__global__ __launch_bounds__(256, 1) void k_rec(
    const _Float16* __restrict__ expb, const _Float16* __restrict__ Wall,
    const float* __restrict__ bsum, _Float16* __restrict__ hcat,
    int* __restrict__ flags, int L) {
  __shared__ _Float16 Ash[64][392];  // [batch][ x(128) | h(256) ] + 8 pad (16B-aligned rows)
  int tid = threadIdx.x;
  int ds = blockIdx.x;
  int dir = ds >> 2, slice = ds & 3;
  int w = tid >> 6, lane = tid & 63;
  int c = lane & 15, kg = lane >> 4;

  // --- one-time init ---
  for (int i = tid; i < 64 * 392 / 8; i += 256)
    ((half8*)&Ash[0][0])[i] = half8{0, 0, 0, 0, 0, 0, 0, 0};
  float bias[4];
#pragma unroll
  for (int g = 0; g < 4; ++g)
    bias[g] = bsum[dir * 1024 + g * 256 + slice * 64 + w * 16 + c];
  half8 breg[4][12];
#pragma unroll
  for (int g = 0; g < 4; ++g) {
    int nt = w + 4 * g;
#pragma unroll
    for (int kt = 0; kt < 12; ++kt)
      breg[g][kt] = *(const half8*)(Wall + (((size_t)(ds * 16 + nt) * 12 + kt) * 64 + lane) * 8);
  }
  float creg[16];
#pragma unroll
  for (int i = 0; i < 16; ++i) creg[i] = 0.f;
  __syncthreads();
  {  // x_0 into Ash[:,0:128]
    int l0 = dir ? (L - 1) : 0;
#pragma unroll
    for (int r = 0; r < 4; ++r) {
      int f = tid + 256 * r;
      int b = f >> 4, ch = f & 15;
      *(half8*)&Ash[b][ch * 8] = *(const half8*)(expb + ((size_t)b * L + l0) * EMB_ + ch * 8);
    }
  }
  __syncthreads();

  for (int s = 0; s < L; ++s) {
    int l_io = dir ? (L - 1 - s) : s;
    _Float16 hv[16];
    // --- GEMM (A=[x_t|h] from LDS, B resident in VGPRs) + fused cell update ---
#pragma unroll
    for (int mp = 0; mp < 2; ++mp) {
      f32x4 acc[2][4];
#pragma unroll
      for (int mm = 0; mm < 2; ++mm)
#pragma unroll
        for (int g = 0; g < 4; ++g) acc[mm][g] = f32x4{0.f, 0.f, 0.f, 0.f};
#pragma unroll
      for (int kt = 0; kt < 12; ++kt) {
        half8 a0 = *(const half8*)&Ash[mp * 32 + c][kt * 32 + kg * 8];
        half8 a1 = *(const half8*)&Ash[mp * 32 + 16 + c][kt * 32 + kg * 8];
#pragma unroll
        for (int g = 0; g < 4; ++g) {
          acc[0][g] = __builtin_amdgcn_mfma_f32_16x16x32_f16(a0, breg[g][kt], acc[0][g], 0, 0, 0);
          acc[1][g] = __builtin_amdgcn_mfma_f32_16x16x32_f16(a1, breg[g][kt], acc[1][g], 0, 0, 0);
        }
      }
#pragma unroll
      for (int mm = 0; mm < 2; ++mm) {
#pragma unroll
        for (int i = 0; i < 4; ++i) {
          int m = mp * 2 + mm;
          float iv = acc[mm][0][i] + bias[0];
          float fv = acc[mm][1][i] + bias[1];
          float gv = acc[mm][2][i] + bias[2];
          float ov = acc[mm][3][i] + bias[3];
          float cc = sigf(fv) * creg[m * 4 + i] + sigf(iv) * tanhf_(gv);
          float hh = sigf(ov) * tanhf_(cc);
          creg[m * 4 + i] = cc;
          hv[m * 4 + i] = (_Float16)hh;
        }
      }
    }
    // --- publish h_s to hcat (also the inter-slice exchange buffer) ---
#pragma unroll
    for (int m = 0; m < 4; ++m)
#pragma unroll
      for (int i = 0; i < 4; ++i) {
        int b = m * 16 + kg * 4 + i;
        hcat[((size_t)b * L + l_io) * 512 + dir * 256 + slice * 64 + w * 16 + c] = hv[m * 4 + i];
      }
    __threadfence();
    __syncthreads();
    if (s == L - 1) break;
    if (tid == 0)
      __hip_atomic_store(&flags[ds * 32], s + 1, __ATOMIC_RELEASE, __HIP_MEMORY_SCOPE_AGENT);
    // issue x_{s+1} loads early (latency hides under the poll)
    half8 xr[4];
    {
      int l1 = dir ? (L - 2 - s) : (s + 1);
#pragma unroll
      for (int r = 0; r < 4; ++r) {
        int f = tid + 256 * r;
        int b = f >> 4, ch = f & 15;
        xr[r] = *(const half8*)(expb + ((size_t)b * L + l1) * EMB_ + ch * 8);
      }
    }
    // own h_s into Ash
#pragma unroll
    for (int m = 0; m < 4; ++m)
#pragma unroll
      for (int i = 0; i < 4; ++i)
        Ash[m * 16 + kg * 4 + i][EMB_ + slice * 64 + w * 16 + c] = hv[m * 4 + i];
    // wait for the 3 peer slices of this dir
    if (tid < 3) {
      int pslice = tid + (tid >= slice ? 1 : 0);
      const int* fp = flags + (dir * 4 + pslice) * 32;
      while (__hip_atomic_load(fp, __ATOMIC_ACQUIRE, __HIP_MEMORY_SCOPE_AGENT) <= s)
        __builtin_amdgcn_s_sleep(2);
    }
    __syncthreads();
    __threadfence();
    // x_{s+1} into Ash
#pragma unroll
    for (int r = 0; r < 4; ++r) {
      int f = tid + 256 * r;
      int b = f >> 4, ch = f & 15;
      *(half8*)&Ash[b][ch * 8] = xr[r];
    }
    // remote h_s slices into Ash (24 octs x 64 batches = 6 half8/thread)
#pragma unroll
    for (int r = 0; r < 6; ++r) {
      int f = tid + 256 * r;
      int b = f / 24;
      int oct = f % 24;
      int u = oct * 8;
      if (u >= slice * 64) u += 64;
      half8 v = *(const half8*)(hcat + ((size_t)b * L + l_io) * 512 + dir * 256 + u);
      *(half8*)&Ash[b][EMB_ + u] = v;
    }
    __syncthreads();
  }
}

// out[r,:80] = hcat[r,:512] @ lin_w.T + lin_b ; one wave per 16-row M-tile
__global__ __launch_bounds__(256) void k_linear(
    const _Float16* __restrict__ hcat, const _Float16* __restrict__ linWp,
    const float* __restrict__ lin_b, float* __restrict__ out, int L) {
  int tid = threadIdx.x;
  int wv = tid >> 6, lane = tid & 63;
  int arow = lane & 15, kgrp = lane >> 4;
  int mt = blockIdx.x * 4 + wv;  // < 4L
  half8 a[16];
  const _Float16* abase = hcat + (size_t)(mt * 16 + arow) * 512 + kgrp * 8;
#pragma unroll
  for (int kt = 0; kt < 16; ++kt) a[kt] = *(const half8*)(abase + kt * 32);
#pragma unroll
  for (int nt = 0; nt < 5; ++nt) {
    f32x4 acc = {0.f, 0.f, 0.f, 0.f};
    const half8* Bp = (const half8*)(linWp + (size_t)nt * 16 * 512) + lane;
#pragma unroll
    for (int kt = 0; kt < 16; ++kt)
      acc = __builtin_amdgcn_mfma_f32_16x16x32_f16(a[kt], Bp[kt * 64], acc, 0, 0, 0);
    int col = nt * 16 + arow;
    float bb = lin_b[col];
#pragma unroll
    for (int i = 0; i < 4; ++i)
      out[(size_t)(mt * 16 + kgrp * 4 + i) * MEL_ + col] = acc[i] + bb;
  }
}

extern "C" void kernel_launch(void* const* d_in, const int* in_sizes, int n_in,
                              void* d_out, int out_size, void* d_ws, size_t ws_size,
                              hipStream_t stream) {
  const int* x = (const int*)d_in[0];
  const float* embed = (const float*)d_in[1];
  const float* dp_w = (const float*)d_in[2];
  const float* dp_b = (const float*)d_in[3];
  const float* wih_f = (const float*)d_in[4];
  const float* whh_f = (const float*)d_in[5];
  const float* bih_f = (const float*)d_in[6];
  const float* bhh_f = (const float*)d_in[7];
  const float* wih_b = (const float*)d_in[8];
  const float* whh_b = (const float*)d_in[9];
  const float* bih_b = (const float*)d_in[10];
  const float* bhh_b = (const float*)d_in[11];
  const float* lin_w = (const float*)d_in[12];
  const float* lin_b = (const float*)d_in[13];
  float* out = (float*)d_out;
  (void)in_sizes; (void)n_in; (void)ws_size;

  int L = out_size / (B_ * MEL_);
  char* base = (char*)d_ws;
  size_t o = 0;
  auto take = [&](size_t bytes) {
    void* p = base + o;
    o = (o + bytes + 255) & ~(size_t)255;
    return p;
  };
  int* dur = (int*)take((size_t)B_ * T_ * 4);
  int* cum = (int*)take((size_t)B_ * T_ * 4);
  int* idx = (int*)take((size_t)B_ * L * 4);
  _Float16* Wall = (_Float16*)take((size_t)8 * 16 * 12 * 512 * 2);
  float* bsum = (float*)take(2048 * 4);
  _Float16* linWp = (_Float16*)take((size_t)5 * 16 * 512 * 2);
  int* flags = (int*)take(256 * 4);
  _Float16* expb = (_Float16*)take((size_t)B_ * L * EMB_ * 2);
  _Float16* hcat = (_Float16*)take((size_t)B_ * L * 512 * 2);

  hipLaunchKernelGGL(k_pack_wall, dim3(384), dim3(256), 0, stream, wih_f, whh_f, wih_b, whh_b, Wall);
  hipLaunchKernelGGL(k_pack_misc, dim3(28), dim3(256), 0, stream, bih_f, bhh_f, bih_b, bhh_b,
                     lin_w, bsum, linWp);
  hipLaunchKernelGGL(k_dur, dim3(128), dim3(256), 0, stream, x, embed, dp_w, dp_b, dur);
  hipLaunchKernelGGL(k_scan, dim3(64), dim3(512), 0, stream, dur, cum);
  hipLaunchKernelGGL(k_fill, dim3((B_ * L + 255) / 256), dim3(256), 0, stream, idx, B_ * L, -1);
  hipLaunchKernelGGL(k_fill, dim3(1), dim3(256), 0, stream, flags, 256, 0);
  hipLaunchKernelGGL(k_scatter, dim3(64), dim3(512), 0, stream, cum, idx, L);
  hipLaunchKernelGGL(k_expand, dim3((B_ * L * 16 + 255) / 256), dim3(256), 0, stream,
                     x, embed, idx, expb, L);
  hipLaunchKernelGGL(k_rec, dim3(8), dim3(256), 0, stream, expb, Wall, bsum, hcat, flags, L);
  hipLaunchKernelGGL(k_linear, dim3(L), dim3(256), 0, stream, hcat, linWp, lin_b, out, L);
}